// Round 3
// baseline (1028.903 us; speedup 1.0000x reference)
//
#include <hip/hip_runtime.h>

typedef _Float16 h16;
typedef _Float16 v8h __attribute__((ext_vector_type(8)));
typedef float    v4f __attribute__((ext_vector_type(4)));
typedef unsigned long long u64;

// qh is pre-scaled by SCALE*log2e = 0.125*1.4426950 at proj time, so
// softmax is p = exp2(s) with zero per-element scaling ops.
constexpr float QPRESCALE = 0.18033688f;

#define MFMA16(a,b,c) __builtin_amdgcn_mfma_f32_16x16x32_f16((a),(b),(c),0,0,0)

__device__ __forceinline__ float fexp2(float x) {
#if __has_builtin(__builtin_amdgcn_exp2f)
    return __builtin_amdgcn_exp2f(x);
#else
    return __expf(x * 0.69314718056f);
#endif
}
__device__ __forceinline__ float flog2(float x) {
#if __has_builtin(__builtin_amdgcn_logf)
    return __builtin_amdgcn_logf(x);
#else
    return __logf(x) * 1.44269504f;
#endif
}

// async global->LDS, 16B per lane. dst must be the WAVE-UNIFORM base; HW adds lane*16.
__device__ __forceinline__ void gld16(const h16* g, const h16* l)
{
    __builtin_amdgcn_global_load_lds(
        (const __attribute__((address_space(1))) void*)g,
        (__attribute__((address_space(3))) void*)l, 16, 0, 0);
}

// ---------------------------------------------------------------------------
// fp32 -> fp16 elementwise (vector4). n = 16777216 per tensor.
// ---------------------------------------------------------------------------
__global__ __launch_bounds__(256)
void cvt16(const float* __restrict__ x, h16* __restrict__ y)
{
    size_t i = ((size_t)blockIdx.x * 256 + threadIdx.x) * 4;
    float4 v = *(const float4*)(x + i);
    h16 o[4] = {(h16)v.x, (h16)v.y, (h16)v.z, (h16)v.w};
    *(uint2*)(y + i) = *(const uint2*)o;
}

// ---------------------------------------------------------------------------
// mask fp32 [bs][lq][lk] -> bitmask, one u64 per 64 consecutive lk.
// ---------------------------------------------------------------------------
__global__ __launch_bounds__(256)
void mkbits(const float* __restrict__ mask, u64* __restrict__ mb)
{
    size_t i = (size_t)blockIdx.x * 256 + threadIdx.x;
    float v = mask[i];
    u64 b = __ballot(v != 0.0f);
    if ((threadIdx.x & 63) == 0) mb[i >> 6] = b;
}

// ---------------------------------------------------------------------------
// W[1024][1024] fp32 -> WT[n][k] fp16 (transposed, for MFMA B-operand).
// ---------------------------------------------------------------------------
__global__ __launch_bounds__(256)
void wtrans(const float* __restrict__ W, h16* __restrict__ WT)
{
    __shared__ float Ts[64][65];
    const int tid = threadIdx.x;
    const int n0 = blockIdx.x * 64, k0 = blockIdx.y * 64;
    #pragma unroll
    for (int i = 0; i < 4; ++i) {
        int f = tid + i * 256; int r = f >> 4, c = (f & 15) * 4;
        float4 v = *(const float4*)(W + (size_t)(k0 + r) * 1024 + n0 + c);
        Ts[r][c] = v.x; Ts[r][c+1] = v.y; Ts[r][c+2] = v.z; Ts[r][c+3] = v.w;
    }
    __syncthreads();
    #pragma unroll
    for (int i = 0; i < 4; ++i) {
        int f = tid + i * 256; int r = f >> 4, c = (f & 15) * 4;
        h16 o[4];
        #pragma unroll
        for (int j = 0; j < 4; ++j) o[j] = (h16)Ts[c + j][r];
        *(uint2*)(WT + (size_t)(n0 + r) * 1024 + k0 + c) = *(const uint2*)o;
    }
}

// ---------------------------------------------------------------------------
// Projection GEMM: Y = A[16384,1024](fp16) @ BT^T + bias, 128x128 block tile,
// 4 waves, m97-structure staging (global_load_lds width-16, linear LDS).
// mode 0  : Y -> head-split fp16 [bs*16+h][l][64], PRE-SCALED by QPRESCALE (qh)
// mode 1  : Y -> head-split fp16 [bs*16+h][l][64]   (kh)
// mode 2  : Y -> transposed fp16 [bs*16+h][64][l]   (vt, for PV B-operand)
// mode 3  : Y -> fp32 row-major  [m][1024]          (final output)
// ---------------------------------------------------------------------------
__global__ __launch_bounds__(256)
void proj(const h16* __restrict__ A, const h16* __restrict__ BT,
          const float* __restrict__ bias, void* __restrict__ out, int mode)
{
    __shared__ h16 As[128 * 32];
    __shared__ h16 Bs[128 * 32];
    const int tid  = threadIdx.x;
    const int lane = tid & 63, wv = tid >> 6;
    const int quad = lane >> 4, l16 = lane & 15;
    const int m0 = blockIdx.y * 128, n0 = blockIdx.x * 128;
    const int wm = (wv & 1) * 64, wn = (wv >> 1) * 64;
    const int sr = wv * 16 + (lane >> 2);
    const int sc = (lane & 3) * 8;
    v4f acc[4][4] = {};
    for (int k0 = 0; k0 < 1024; k0 += 32) {
        #pragma unroll
        for (int i = 0; i < 2; ++i) {
            int r = i * 64 + sr;
            gld16(A  + (size_t)(m0 + r) * 1024 + k0 + sc, &As[i * 2048 + wv * 512]);
            gld16(BT + (size_t)(n0 + r) * 1024 + k0 + sc, &Bs[i * 2048 + wv * 512]);
        }
        __syncthreads();
        v8h af[4], bf[4];
        #pragma unroll
        for (int t = 0; t < 4; ++t) {
            af[t] = *(v8h*)&As[(wm + t*16 + l16) * 32 + quad * 8];
            bf[t] = *(v8h*)&Bs[(wn + t*16 + l16) * 32 + quad * 8];
        }
        #pragma unroll
        for (int mt = 0; mt < 4; ++mt)
            #pragma unroll
            for (int nt = 0; nt < 4; ++nt)
                acc[mt][nt] = MFMA16(af[mt], bf[nt], acc[mt][nt]);
        __syncthreads();
    }
    #pragma unroll
    for (int mt = 0; mt < 4; ++mt) {
        int mbase = m0 + wm + mt*16 + quad*4;
        #pragma unroll
        for (int nt = 0; nt < 4; ++nt) {
            int n = n0 + wn + nt*16 + l16;
            float bv = bias[n];
            #pragma unroll
            for (int r = 0; r < 4; ++r) {
                float y = acc[mt][nt][r] + bv;
                if (mode == 0) y *= QPRESCALE;
                int mm = mbase + r;
                int bs = mm >> 10, l = mm & 1023, h = n >> 6, d = n & 63;
                if (mode <= 1)
                    ((h16*)out)[(((size_t)bs*16 + h) * 1024 + l) * 64 + d] = (h16)y;
                else if (mode == 2)
                    ((h16*)out)[(((size_t)bs*16 + h) * 64 + d) * 1024 + l] = (h16)y;
                else
                    ((float*)out)[(size_t)mm * 1024 + n] = y;
            }
        }
    }
}

// ---------------------------------------------------------------------------
// Fused attention. qh pre-scaled -> p = exp2(S). Row sums via ones-column
// MFMA. K/V reg-prefetched one tile ahead. 2 barriers/kt (Ps is wave-private
// so no softmax->PV barrier). XCD remap: the 8 q-blocks of one bsh are
// CONSECUTIVE slots on one XCD -> K/V stay L2-resident across their reuse.
// Lst stores log2(rowsum) for the attn_mean pass.
// ---------------------------------------------------------------------------
__global__ __launch_bounds__(256, 3)
void attn_ctx(const h16* __restrict__ qh, const h16* __restrict__ kh,
              const h16* __restrict__ vt, const u64* __restrict__ mbits,
              h16* __restrict__ ctx, float* __restrict__ Lst)
{
    __shared__ h16 Qs[128][68];
    __shared__ h16 Ks[64][68];
    __shared__ h16 Vs[64][68];
    __shared__ h16 Ps[128][68];
    const int tid  = threadIdx.x;
    const int lane = tid & 63, wv = tid >> 6;
    const int quad = lane >> 4, l16 = lane & 15;
    // XCD remap: xcd = orig&7; within an XCD, qb varies fastest (8 consecutive
    // slots share one bsh => its 256KB K/V is L2-resident while reused).
    const int orig = blockIdx.x + (blockIdx.y << 8);
    const int slot = orig >> 3;
    const int bsh  = (orig & 7) + ((slot >> 3) << 3);
    const int qb   = (slot & 7) << 7;
    const int bs = bsh >> 4, h = bsh & 15;
    const int qw = wv * 32;
    const int fr = tid >> 3, fc = (tid & 7) * 8;

    // prefetch k-tile 0 into regs
    uint4 rK0 = *(const uint4*)(kh + ((size_t)bsh*1024 + fr     ) * 64 + fc);
    uint4 rK1 = *(const uint4*)(kh + ((size_t)bsh*1024 + fr + 32) * 64 + fc);
    uint4 rV0 = *(const uint4*)(vt + ((size_t)bsh*64 + fr     ) * 1024 + fc);
    uint4 rV1 = *(const uint4*)(vt + ((size_t)bsh*64 + fr + 32) * 1024 + fc);

    #pragma unroll
    for (int i = 0; i < 4; ++i) {
        int f = tid + i * 256; int r = f >> 3, c = (f & 7) * 8;
        *(uint4*)&Qs[r][c] = *(const uint4*)(qh + ((size_t)bsh*1024 + qb + r) * 64 + c);
    }
    v8h bones;
    {
        h16 o = (l16 == 0) ? (h16)1.0f : (h16)0.0f;
        #pragma unroll
        for (int j = 0; j < 8; ++j) bones[j] = o;
    }
    const u64* mrb = mbits + ((size_t)bs*1024 + qb + qw + quad*4) * 16;

    v4f accp[2][4] = {};
    v4f accs[2] = {};
    for (int kt = 0; kt < 16; ++kt) {
        __syncthreads();
        *(uint4*)&Ks[fr     ][fc] = rK0;
        *(uint4*)&Ks[fr + 32][fc] = rK1;
        *(uint4*)&Vs[fr     ][fc] = rV0;
        *(uint4*)&Vs[fr + 32][fc] = rV1;
        if (kt < 15) {   // issue next tile; latency hides under QK+softmax+PV
            rK0 = *(const uint4*)(kh + ((size_t)bsh*1024 + (kt+1)*64 + fr     ) * 64 + fc);
            rK1 = *(const uint4*)(kh + ((size_t)bsh*1024 + (kt+1)*64 + fr + 32) * 64 + fc);
            rV0 = *(const uint4*)(vt + ((size_t)bsh*64 + fr     ) * 1024 + (kt+1)*64 + fc);
            rV1 = *(const uint4*)(vt + ((size_t)bsh*64 + fr + 32) * 1024 + (kt+1)*64 + fc);
        }
        __syncthreads();
        v4f s[2][4] = {};
        #pragma unroll
        for (int kc = 0; kc < 2; ++kc) {
            v8h aq[2], bk[4];
            aq[0] = *(v8h*)&Qs[qw      + l16][kc*32 + quad*8];
            aq[1] = *(v8h*)&Qs[qw + 16 + l16][kc*32 + quad*8];
            #pragma unroll
            for (int nt = 0; nt < 4; ++nt)
                bk[nt] = *(v8h*)&Ks[nt*16 + l16][kc*32 + quad*8];
            #pragma unroll
            for (int mt = 0; mt < 2; ++mt)
                #pragma unroll
                for (int nt = 0; nt < 4; ++nt)
                    s[mt][nt] = MFMA16(aq[mt], bk[nt], s[mt][nt]);
        }
        #pragma unroll
        for (int mt = 0; mt < 2; ++mt)
            #pragma unroll
            for (int r = 0; r < 4; ++r) {
                int ql = qw + mt*16 + quad*4 + r;
                u64 m64 = mrb[(mt*16 + r) * 16 + kt];
                uint lo = (uint)(m64 >> l16);
                uint hi = (uint)(m64 >> (l16 + 32));
                #pragma unroll
                for (int nt = 0; nt < 4; ++nt) {
                    uint b = (((nt & 2) ? hi : lo) >> ((nt & 1) * 16)) & 1u;
                    float p = b ? 0.0f : fexp2(s[mt][nt][r]);
                    Ps[ql][nt*16 + l16] = (h16)p;
                }
            }
        // NO barrier here: Ps rows [qw, qw+32) are written and read only by
        // this wave; compiler's lgkmcnt ordering covers the LDS RAW.
        #pragma unroll
        for (int kc = 0; kc < 2; ++kc) {
            v8h ap[2], bv[4];
            ap[0] = *(v8h*)&Ps[qw      + l16][kc*32 + quad*8];
            ap[1] = *(v8h*)&Ps[qw + 16 + l16][kc*32 + quad*8];
            #pragma unroll
            for (int nt = 0; nt < 4; ++nt)
                bv[nt] = *(v8h*)&Vs[nt*16 + l16][kc*32 + quad*8];
            #pragma unroll
            for (int mt = 0; mt < 2; ++mt) {
                accs[mt] = MFMA16(ap[mt], bones, accs[mt]);   // row sums
                #pragma unroll
                for (int nt = 0; nt < 4; ++nt)
                    accp[mt][nt] = MFMA16(ap[mt], bv[nt], accp[mt][nt]);
            }
        }
    }
    // row sums live in l16==0 lanes of accs: store log2(l), broadcast, normalize.
    float lq[8];
    #pragma unroll
    for (int mt = 0; mt < 2; ++mt)
        #pragma unroll
        for (int r = 0; r < 4; ++r)
            lq[mt*4 + r] = accs[mt][r];
    if (l16 == 0) {
        #pragma unroll
        for (int j = 0; j < 8; ++j)
            Lst[(size_t)bsh*1024 + qb + qw + (j >> 2)*16 + quad*4 + (j & 3)]
                = flog2(lq[j]);
    }
    float rcp[8];
    #pragma unroll
    for (int j = 0; j < 8; ++j) {
        float l = __shfl(lq[j], quad * 16);
        rcp[j] = 1.0f / l;
    }
    #pragma unroll
    for (int mt = 0; mt < 2; ++mt)
        #pragma unroll
        for (int nt = 0; nt < 4; ++nt) {
            int dep = nt*16 + l16;
            #pragma unroll
            for (int r = 0; r < 4; ++r) {
                int ql = qw + mt*16 + quad*4 + r;
                float y = accp[mt][nt][r] * rcp[mt*4 + r];
                ctx[((size_t)bs*1024 + qb + ql) * 1024 + h*64 + dep] = (h16)y;
            }
        }
}

// ---------------------------------------------------------------------------
// attn_mean: per (bs, 128-q block, 64-k tile) loop all 16 heads in-block.
// Lst already holds log2(l) -> inner loop is sub+exp2+add only. Next head's
// Q/K reg-prefetched (T14). XCD remap: one bs per XCD run (4MB = L2), kt
// varies fastest so each Q-tile's 16 kt reuses are time-adjacent.
// ---------------------------------------------------------------------------
__global__ __launch_bounds__(256)
void attn_mean_k(const h16* __restrict__ qh, const h16* __restrict__ kh,
                 const u64* __restrict__ mbits, const float* __restrict__ Lst,
                 float* __restrict__ am)
{
    __shared__ h16 Qs[128][68];
    __shared__ h16 Ks[64][68];
    const int tid  = threadIdx.x;
    const int lane = tid & 63, wv = tid >> 6;
    const int quad = lane >> 4, l16 = lane & 15;
    // XCD remap: xcd = orig&7; slot walks kt fastest, then qb, then bs-half.
    const int orig = blockIdx.x + (blockIdx.y << 4) + (blockIdx.z << 7);
    const int slot = orig >> 3;
    const int bs   = ((orig & 7) << 1) + (slot >> 7);
    const int kt   = slot & 15;
    const int qb   = ((slot >> 4) & 7) << 7;
    const int qw = wv * 32;
    u64 mrow[2][4];
    #pragma unroll
    for (int mt = 0; mt < 2; ++mt)
        #pragma unroll
        for (int r = 0; r < 4; ++r) {
            int ql = qw + mt*16 + quad*4 + r;
            mrow[mt][r] = mbits[((size_t)bs*1024 + qb + ql) * 16 + kt];
        }
    const int pr = tid >> 3, pc = (tid & 7) * 8;
    uint4 rq[4], rk[2];
    {
        const size_t bsh0 = (size_t)bs * 16;
        #pragma unroll
        for (int i = 0; i < 4; ++i)
            rq[i] = *(const uint4*)(qh + (bsh0*1024 + qb + pr + 32*i) * 64 + pc);
        #pragma unroll
        for (int i = 0; i < 2; ++i)
            rk[i] = *(const uint4*)(kh + (bsh0*1024 + kt*64 + pr + 32*i) * 64 + pc);
    }
    float acc[2][4][4] = {};
    for (int h = 0; h < 16; ++h) {
        const int bsh = bs * 16 + h;
        __syncthreads();
        #pragma unroll
        for (int i = 0; i < 4; ++i) *(uint4*)&Qs[pr + 32*i][pc] = rq[i];
        #pragma unroll
        for (int i = 0; i < 2; ++i) *(uint4*)&Ks[pr + 32*i][pc] = rk[i];
        if (h < 15) {   // prefetch next head; hides under MFMA+exp below
            const size_t bshn = (size_t)bsh + 1;
            #pragma unroll
            for (int i = 0; i < 4; ++i)
                rq[i] = *(const uint4*)(qh + (bshn*1024 + qb + pr + 32*i) * 64 + pc);
            #pragma unroll
            for (int i = 0; i < 2; ++i)
                rk[i] = *(const uint4*)(kh + (bshn*1024 + kt*64 + pr + 32*i) * 64 + pc);
        }
        __syncthreads();
        v4f s[2][4] = {};
        #pragma unroll
        for (int kc = 0; kc < 2; ++kc) {
            v8h aq[2], bk[4];
            aq[0] = *(v8h*)&Qs[qw      + l16][kc*32 + quad*8];
            aq[1] = *(v8h*)&Qs[qw + 16 + l16][kc*32 + quad*8];
            #pragma unroll
            for (int nt = 0; nt < 4; ++nt)
                bk[nt] = *(v8h*)&Ks[nt*16 + l16][kc*32 + quad*8];
            #pragma unroll
            for (int mt = 0; mt < 2; ++mt)
                #pragma unroll
                for (int nt = 0; nt < 4; ++nt)
                    s[mt][nt] = MFMA16(aq[mt], bk[nt], s[mt][nt]);
        }
        float ll[8];
        #pragma unroll
        for (int mt = 0; mt < 2; ++mt)
            #pragma unroll
            for (int r = 0; r < 4; ++r)
                ll[mt*4+r] = Lst[(size_t)bsh*1024 + qb + qw + mt*16 + quad*4 + r];
        #pragma unroll
        for (int mt = 0; mt < 2; ++mt)
            #pragma unroll
            for (int nt = 0; nt < 4; ++nt)
                #pragma unroll
                for (int r = 0; r < 4; ++r)
                    acc[mt][nt][r] += fexp2(s[mt][nt][r] - ll[mt*4+r]);
    }
    #pragma unroll
    for (int mt = 0; mt < 2; ++mt)
        #pragma unroll
        for (int r = 0; r < 4; ++r) {
            int ql = qw + mt*16 + quad*4 + r;
            uint lo = (uint)(mrow[mt][r] >> l16);
            uint hi = (uint)(mrow[mt][r] >> (l16 + 32));
            #pragma unroll
            for (int nt = 0; nt < 4; ++nt) {
                uint b = (((nt & 2) ? hi : lo) >> ((nt & 1) * 16)) & 1u;
                am[((size_t)bs*1024 + qb + ql) * 1024 + kt*64 + nt*16 + l16]
                    = b ? 0.0f : acc[mt][nt][r] * 0.0625f;
            }
        }
}

// ---------------------------------------------------------------------------
extern "C" void kernel_launch(void* const* d_in, const int* in_sizes, int n_in,
                              void* d_out, int out_size, void* d_ws, size_t ws_size,
                              hipStream_t stream)
{
    const float* q    = (const float*)d_in[0];
    const float* k    = (const float*)d_in[1];
    const float* v    = (const float*)d_in[2];
    const float* mask = (const float*)d_in[3];
    const float* wq   = (const float*)d_in[4];
    const float* bq   = (const float*)d_in[5];
    const float* wk   = (const float*)d_in[6];
    const float* bk   = (const float*)d_in[7];
    const float* wv   = (const float*)d_in[8];
    const float* bv   = (const float*)d_in[9];
    const float* wo   = (const float*)d_in[10];
    const float* bo   = (const float*)d_in[11];

    const size_t TEN = (size_t)16384 * 1024;       // 16.78M elements
    char* w = (char*)d_ws;
    h16* qf  = (h16*)w;             w += TEN * 2;  // inputs, fp16
    h16* kf  = (h16*)w;             w += TEN * 2;
    h16* vf  = (h16*)w;             w += TEN * 2;
    h16* wqT = (h16*)w;             w += (size_t)1024*1024*2;
    h16* wkT = (h16*)w;             w += (size_t)1024*1024*2;
    h16* wvT = (h16*)w;             w += (size_t)1024*1024*2;
    h16* woT = (h16*)w;             w += (size_t)1024*1024*2;
    h16* qhh = (h16*)w;             w += TEN * 2;  // [bsh][l][64], pre-scaled
    h16* khh = (h16*)w;             w += TEN * 2;
    h16* vtt = (h16*)w;             w += TEN * 2;  // [bsh][64][l]
    h16* ctx = (h16*)w;             w += TEN * 2;  // [bs][l][1024]
    float* Lst = (float*)w;         w += (size_t)256 * 1024 * 4;   // [bsh][l], log2
    u64* mbits = (u64*)w;                          // [bs][l][16] qwords, 2MB

    float* out = (float*)d_out;
    float* am  = out + TEN;

    mkbits<<<65536, 256, 0, stream>>>(mask, mbits);
    cvt16<<<16384, 256, 0, stream>>>(q, qf);
    cvt16<<<16384, 256, 0, stream>>>(k, kf);
    cvt16<<<16384, 256, 0, stream>>>(v, vf);
    wtrans<<<dim3(16,16), 256, 0, stream>>>(wq, wqT);
    wtrans<<<dim3(16,16), 256, 0, stream>>>(wk, wkT);
    wtrans<<<dim3(16,16), 256, 0, stream>>>(wv, wvT);
    wtrans<<<dim3(16,16), 256, 0, stream>>>(wo, woT);
    proj<<<dim3(8,128), 256, 0, stream>>>(qf, wqT, bq, qhh, 0);
    proj<<<dim3(8,128), 256, 0, stream>>>(kf, wkT, bk, khh, 1);
    proj<<<dim3(8,128), 256, 0, stream>>>(vf, wvT, bv, vtt, 2);
    attn_ctx<<<dim3(256,8), 256, 0, stream>>>(qhh, khh, vtt, mbits, ctx, Lst);
    attn_mean_k<<<dim3(16,8,16), 256, 0, stream>>>(qhh, khh, mbits, Lst, am);
    proj<<<dim3(8,128), 256, 0, stream>>>(ctx, woT, bo, out, 3);
}

// Round 4
// 835.561 us; speedup vs baseline: 1.2314x; 1.2314x over previous
//
#include <hip/hip_runtime.h>

typedef _Float16 h16;
typedef _Float16 v8h __attribute__((ext_vector_type(8)));
typedef float    v4f __attribute__((ext_vector_type(4)));
typedef unsigned long long u64;

// qh is pre-scaled by SCALE*log2e = 0.125*1.4426950 at proj time, so
// softmax is p = exp2(s) with zero per-element scaling ops.
constexpr float QPRESCALE = 0.18033688f;

#define MFMA16(a,b,c) __builtin_amdgcn_mfma_f32_16x16x32_f16((a),(b),(c),0,0,0)

__device__ __forceinline__ float fexp2(float x) {
#if __has_builtin(__builtin_amdgcn_exp2f)
    return __builtin_amdgcn_exp2f(x);
#else
    return __expf(x * 0.69314718056f);
#endif
}
__device__ __forceinline__ float flog2(float x) {
#if __has_builtin(__builtin_amdgcn_logf)
    return __builtin_amdgcn_logf(x);
#else
    return __logf(x) * 1.44269504f;
#endif
}

// async global->LDS, 16B per lane. dst must be the WAVE-UNIFORM base; HW adds lane*16.
__device__ __forceinline__ void gld16(const h16* g, const h16* l)
{
    __builtin_amdgcn_global_load_lds(
        (const __attribute__((address_space(1))) void*)g,
        (__attribute__((address_space(3))) void*)l, 16, 0, 0);
}

// ---------------------------------------------------------------------------
// fp32 -> fp16 elementwise (vector4). n = 16777216 per tensor.
// ---------------------------------------------------------------------------
__global__ __launch_bounds__(256)
void cvt16(const float* __restrict__ x, h16* __restrict__ y)
{
    size_t i = ((size_t)blockIdx.x * 256 + threadIdx.x) * 4;
    float4 v = *(const float4*)(x + i);
    h16 o[4] = {(h16)v.x, (h16)v.y, (h16)v.z, (h16)v.w};
    *(uint2*)(y + i) = *(const uint2*)o;
}

// ---------------------------------------------------------------------------
// mask fp32 [bs][lq][lk] -> bitmask, one u64 per 64 consecutive lk.
// ---------------------------------------------------------------------------
__global__ __launch_bounds__(256)
void mkbits(const float* __restrict__ mask, u64* __restrict__ mb)
{
    size_t i = (size_t)blockIdx.x * 256 + threadIdx.x;
    float v = mask[i];
    u64 b = __ballot(v != 0.0f);
    if ((threadIdx.x & 63) == 0) mb[i >> 6] = b;
}

// ---------------------------------------------------------------------------
// W[1024][1024] fp32 -> WT[n][k] fp16 (transposed, for MFMA B-operand).
// ---------------------------------------------------------------------------
__global__ __launch_bounds__(256)
void wtrans(const float* __restrict__ W, h16* __restrict__ WT)
{
    __shared__ float Ts[64][65];
    const int tid = threadIdx.x;
    const int n0 = blockIdx.x * 64, k0 = blockIdx.y * 64;
    #pragma unroll
    for (int i = 0; i < 4; ++i) {
        int f = tid + i * 256; int r = f >> 4, c = (f & 15) * 4;
        float4 v = *(const float4*)(W + (size_t)(k0 + r) * 1024 + n0 + c);
        Ts[r][c] = v.x; Ts[r][c+1] = v.y; Ts[r][c+2] = v.z; Ts[r][c+3] = v.w;
    }
    __syncthreads();
    #pragma unroll
    for (int i = 0; i < 4; ++i) {
        int f = tid + i * 256; int r = f >> 4, c = (f & 15) * 4;
        h16 o[4];
        #pragma unroll
        for (int j = 0; j < 4; ++j) o[j] = (h16)Ts[c + j][r];
        *(uint2*)(WT + (size_t)(n0 + r) * 1024 + k0 + c) = *(const uint2*)o;
    }
}

// ---------------------------------------------------------------------------
// Projection GEMM: Y = A[16384,1024](fp16) @ BT^T + bias, 128x128 block tile,
// 4 waves, m97-structure staging (global_load_lds width-16, linear LDS).
// mode 0  : Y -> head-split fp16 [bs*16+h][l][64], PRE-SCALED by QPRESCALE (qh)
// mode 1  : Y -> head-split fp16 [bs*16+h][l][64]   (kh)
// mode 2  : Y -> transposed fp16 [bs*16+h][64][l]   (vt, for PV B-operand)
// mode 3  : Y -> fp32 row-major  [m][1024]          (final output)
// ---------------------------------------------------------------------------
__global__ __launch_bounds__(256)
void proj(const h16* __restrict__ A, const h16* __restrict__ BT,
          const float* __restrict__ bias, void* __restrict__ out, int mode)
{
    __shared__ h16 As[128 * 32];
    __shared__ h16 Bs[128 * 32];
    const int tid  = threadIdx.x;
    const int lane = tid & 63, wv = tid >> 6;
    const int quad = lane >> 4, l16 = lane & 15;
    const int m0 = blockIdx.y * 128, n0 = blockIdx.x * 128;
    const int wm = (wv & 1) * 64, wn = (wv >> 1) * 64;
    const int sr = wv * 16 + (lane >> 2);
    const int sc = (lane & 3) * 8;
    v4f acc[4][4] = {};
    for (int k0 = 0; k0 < 1024; k0 += 32) {
        #pragma unroll
        for (int i = 0; i < 2; ++i) {
            int r = i * 64 + sr;
            gld16(A  + (size_t)(m0 + r) * 1024 + k0 + sc, &As[i * 2048 + wv * 512]);
            gld16(BT + (size_t)(n0 + r) * 1024 + k0 + sc, &Bs[i * 2048 + wv * 512]);
        }
        __syncthreads();
        v8h af[4], bf[4];
        #pragma unroll
        for (int t = 0; t < 4; ++t) {
            af[t] = *(v8h*)&As[(wm + t*16 + l16) * 32 + quad * 8];
            bf[t] = *(v8h*)&Bs[(wn + t*16 + l16) * 32 + quad * 8];
        }
        #pragma unroll
        for (int mt = 0; mt < 4; ++mt)
            #pragma unroll
            for (int nt = 0; nt < 4; ++nt)
                acc[mt][nt] = MFMA16(af[mt], bf[nt], acc[mt][nt]);
        __syncthreads();
    }
    #pragma unroll
    for (int mt = 0; mt < 4; ++mt) {
        int mbase = m0 + wm + mt*16 + quad*4;
        #pragma unroll
        for (int nt = 0; nt < 4; ++nt) {
            int n = n0 + wn + nt*16 + l16;
            float bv = bias[n];
            #pragma unroll
            for (int r = 0; r < 4; ++r) {
                float y = acc[mt][nt][r] + bv;
                if (mode == 0) y *= QPRESCALE;
                int mm = mbase + r;
                int bs = mm >> 10, l = mm & 1023, h = n >> 6, d = n & 63;
                if (mode <= 1)
                    ((h16*)out)[(((size_t)bs*16 + h) * 1024 + l) * 64 + d] = (h16)y;
                else if (mode == 2)
                    ((h16*)out)[(((size_t)bs*16 + h) * 64 + d) * 1024 + l] = (h16)y;
                else
                    ((float*)out)[(size_t)mm * 1024 + n] = y;
            }
        }
    }
}

// ---------------------------------------------------------------------------
// Fused attention. qh pre-scaled -> p = exp2(S). Row sums via ones-column
// MFMA. K/V reg-prefetched one tile ahead. 3 barriers/kt (R2-proven form).
// XCD remap: the 8 q-blocks of one bsh are CONSECUTIVE slots on one XCD
// -> K/V stay L2-resident across their reuse.
// Lst stores log2(rowsum) for the attn_mean pass.
// ---------------------------------------------------------------------------
__global__ __launch_bounds__(256, 3)
void attn_ctx(const h16* __restrict__ qh, const h16* __restrict__ kh,
              const h16* __restrict__ vt, const u64* __restrict__ mbits,
              h16* __restrict__ ctx, float* __restrict__ Lst)
{
    __shared__ h16 Qs[128][68];
    __shared__ h16 Ks[64][68];
    __shared__ h16 Vs[64][68];
    __shared__ h16 Ps[128][68];
    const int tid  = threadIdx.x;
    const int lane = tid & 63, wv = tid >> 6;
    const int quad = lane >> 4, l16 = lane & 15;
    // XCD remap: xcd = orig&7; within an XCD, qb varies fastest (8 consecutive
    // slots share one bsh => its 256KB K/V is L2-resident while reused).
    const int orig = blockIdx.x + (blockIdx.y << 8);
    const int slot = orig >> 3;
    const int bsh  = (orig & 7) + ((slot >> 3) << 3);
    const int qb   = (slot & 7) << 7;
    const int bs = bsh >> 4, h = bsh & 15;
    const int qw = wv * 32;
    const int fr = tid >> 3, fc = (tid & 7) * 8;

    // prefetch k-tile 0 into regs
    uint4 rK0 = *(const uint4*)(kh + ((size_t)bsh*1024 + fr     ) * 64 + fc);
    uint4 rK1 = *(const uint4*)(kh + ((size_t)bsh*1024 + fr + 32) * 64 + fc);
    uint4 rV0 = *(const uint4*)(vt + ((size_t)bsh*64 + fr     ) * 1024 + fc);
    uint4 rV1 = *(const uint4*)(vt + ((size_t)bsh*64 + fr + 32) * 1024 + fc);

    #pragma unroll
    for (int i = 0; i < 4; ++i) {
        int f = tid + i * 256; int r = f >> 3, c = (f & 7) * 8;
        *(uint4*)&Qs[r][c] = *(const uint4*)(qh + ((size_t)bsh*1024 + qb + r) * 64 + c);
    }
    v8h bones;
    {
        h16 o = (l16 == 0) ? (h16)1.0f : (h16)0.0f;
        #pragma unroll
        for (int j = 0; j < 8; ++j) bones[j] = o;
    }
    const u64* mrb = mbits + ((size_t)bs*1024 + qb + qw + quad*4) * 16;

    v4f accp[2][4] = {};
    v4f accs[2] = {};
    for (int kt = 0; kt < 16; ++kt) {
        __syncthreads();
        *(uint4*)&Ks[fr     ][fc] = rK0;
        *(uint4*)&Ks[fr + 32][fc] = rK1;
        *(uint4*)&Vs[fr     ][fc] = rV0;
        *(uint4*)&Vs[fr + 32][fc] = rV1;
        if (kt < 15) {   // issue next tile; latency hides under QK+softmax+PV
            rK0 = *(const uint4*)(kh + ((size_t)bsh*1024 + (kt+1)*64 + fr     ) * 64 + fc);
            rK1 = *(const uint4*)(kh + ((size_t)bsh*1024 + (kt+1)*64 + fr + 32) * 64 + fc);
            rV0 = *(const uint4*)(vt + ((size_t)bsh*64 + fr     ) * 1024 + (kt+1)*64 + fc);
            rV1 = *(const uint4*)(vt + ((size_t)bsh*64 + fr + 32) * 1024 + (kt+1)*64 + fc);
        }
        __syncthreads();
        v4f s[2][4] = {};
        #pragma unroll
        for (int kc = 0; kc < 2; ++kc) {
            v8h aq[2], bk[4];
            aq[0] = *(v8h*)&Qs[qw      + l16][kc*32 + quad*8];
            aq[1] = *(v8h*)&Qs[qw + 16 + l16][kc*32 + quad*8];
            #pragma unroll
            for (int nt = 0; nt < 4; ++nt)
                bk[nt] = *(v8h*)&Ks[nt*16 + l16][kc*32 + quad*8];
            #pragma unroll
            for (int mt = 0; mt < 2; ++mt)
                #pragma unroll
                for (int nt = 0; nt < 4; ++nt)
                    s[mt][nt] = MFMA16(aq[mt], bk[nt], s[mt][nt]);
        }
        #pragma unroll
        for (int mt = 0; mt < 2; ++mt)
            #pragma unroll
            for (int r = 0; r < 4; ++r) {
                int ql = qw + mt*16 + quad*4 + r;
                u64 m64 = mrb[(mt*16 + r) * 16 + kt];
                uint lo = (uint)(m64 >> l16);
                uint hi = (uint)(m64 >> (l16 + 32));
                #pragma unroll
                for (int nt = 0; nt < 4; ++nt) {
                    uint b = (((nt & 2) ? hi : lo) >> ((nt & 1) * 16)) & 1u;
                    float p = b ? 0.0f : fexp2(s[mt][nt][r]);
                    Ps[ql][nt*16 + l16] = (h16)p;
                }
            }
        __syncthreads();
        #pragma unroll
        for (int kc = 0; kc < 2; ++kc) {
            v8h ap[2], bv[4];
            ap[0] = *(v8h*)&Ps[qw      + l16][kc*32 + quad*8];
            ap[1] = *(v8h*)&Ps[qw + 16 + l16][kc*32 + quad*8];
            #pragma unroll
            for (int nt = 0; nt < 4; ++nt)
                bv[nt] = *(v8h*)&Vs[nt*16 + l16][kc*32 + quad*8];
            #pragma unroll
            for (int mt = 0; mt < 2; ++mt) {
                accs[mt] = MFMA16(ap[mt], bones, accs[mt]);   // row sums
                #pragma unroll
                for (int nt = 0; nt < 4; ++nt)
                    accp[mt][nt] = MFMA16(ap[mt], bv[nt], accp[mt][nt]);
            }
        }
    }
    // row sums live in l16==0 lanes of accs: store log2(l), broadcast, normalize.
    float lq[8];
    #pragma unroll
    for (int mt = 0; mt < 2; ++mt)
        #pragma unroll
        for (int r = 0; r < 4; ++r)
            lq[mt*4 + r] = accs[mt][r];
    if (l16 == 0) {
        #pragma unroll
        for (int j = 0; j < 8; ++j)
            Lst[(size_t)bsh*1024 + qb + qw + (j >> 2)*16 + quad*4 + (j & 3)]
                = flog2(lq[j]);
    }
    float rcp[8];
    #pragma unroll
    for (int j = 0; j < 8; ++j) {
        float l = __shfl(lq[j], quad * 16);
        rcp[j] = 1.0f / l;
    }
    #pragma unroll
    for (int mt = 0; mt < 2; ++mt)
        #pragma unroll
        for (int nt = 0; nt < 4; ++nt) {
            int dep = nt*16 + l16;
            #pragma unroll
            for (int r = 0; r < 4; ++r) {
                int ql = qw + mt*16 + quad*4 + r;
                float y = accp[mt][nt][r] * rcp[mt*4 + r];
                ctx[((size_t)bs*1024 + qb + ql) * 1024 + h*64 + dep] = (h16)y;
            }
        }
}

// ---------------------------------------------------------------------------
// attn_mean: per (bs, 128-q block, 64-k tile) loop all 16 heads in-block.
// Lst holds log2(l) -> inner loop is sub+exp2+add only. Synchronous LDS
// staging (NO cross-iteration reg prefetch: that spilled acc to scratch in
// R3 -> 639MB scratch writes). mrow bitmask loaded AFTER the h-loop.
// XCD remap: one bs per XCD run (4MB = L2), kt varies fastest.
// ---------------------------------------------------------------------------
__global__ __launch_bounds__(256)
void attn_mean_k(const h16* __restrict__ qh, const h16* __restrict__ kh,
                 const u64* __restrict__ mbits, const float* __restrict__ Lst,
                 float* __restrict__ am)
{
    __shared__ h16 Qs[128][68];
    __shared__ h16 Ks[64][68];
    const int tid  = threadIdx.x;
    const int lane = tid & 63, wv = tid >> 6;
    const int quad = lane >> 4, l16 = lane & 15;
    // XCD remap: xcd = orig&7; slot walks kt fastest, then qb, then bs-half.
    const int orig = blockIdx.x + (blockIdx.y << 4) + (blockIdx.z << 7);
    const int slot = orig >> 3;
    const int bs   = ((orig & 7) << 1) + (slot >> 7);
    const int kt   = slot & 15;
    const int qb   = ((slot >> 4) & 7) << 7;
    const int qw = wv * 32;
    float acc[2][4][4] = {};
    for (int h = 0; h < 16; ++h) {
        const int bsh = bs * 16 + h;
        __syncthreads();
        #pragma unroll
        for (int i = 0; i < 4; ++i) {
            int f = tid + i * 256; int r = f >> 3, c = (f & 7) * 8;
            *(uint4*)&Qs[r][c] = *(const uint4*)(qh + ((size_t)bsh*1024 + qb + r) * 64 + c);
        }
        #pragma unroll
        for (int i = 0; i < 2; ++i) {
            int f = tid + i * 256; int r = f >> 3, c = (f & 7) * 8;
            *(uint4*)&Ks[r][c] = *(const uint4*)(kh + ((size_t)bsh*1024 + kt*64 + r) * 64 + c);
        }
        __syncthreads();
        v4f s[2][4] = {};
        #pragma unroll
        for (int kc = 0; kc < 2; ++kc) {
            v8h aq[2], bk[4];
            aq[0] = *(v8h*)&Qs[qw      + l16][kc*32 + quad*8];
            aq[1] = *(v8h*)&Qs[qw + 16 + l16][kc*32 + quad*8];
            #pragma unroll
            for (int nt = 0; nt < 4; ++nt)
                bk[nt] = *(v8h*)&Ks[nt*16 + l16][kc*32 + quad*8];
            #pragma unroll
            for (int mt = 0; mt < 2; ++mt)
                #pragma unroll
                for (int nt = 0; nt < 4; ++nt)
                    s[mt][nt] = MFMA16(aq[mt], bk[nt], s[mt][nt]);
        }
        float ll[8];
        #pragma unroll
        for (int mt = 0; mt < 2; ++mt)
            #pragma unroll
            for (int r = 0; r < 4; ++r)
                ll[mt*4+r] = Lst[(size_t)bsh*1024 + qb + qw + mt*16 + quad*4 + r];
        #pragma unroll
        for (int mt = 0; mt < 2; ++mt)
            #pragma unroll
            for (int nt = 0; nt < 4; ++nt)
                #pragma unroll
                for (int r = 0; r < 4; ++r)
                    acc[mt][nt][r] += fexp2(s[mt][nt][r] - ll[mt*4+r]);
    }
    #pragma unroll
    for (int mt = 0; mt < 2; ++mt)
        #pragma unroll
        for (int r = 0; r < 4; ++r) {
            int ql = qw + mt*16 + quad*4 + r;
            u64 m64 = mbits[((size_t)bs*1024 + qb + ql) * 16 + kt];
            uint lo = (uint)(m64 >> l16);
            uint hi = (uint)(m64 >> (l16 + 32));
            #pragma unroll
            for (int nt = 0; nt < 4; ++nt) {
                uint b = (((nt & 2) ? hi : lo) >> ((nt & 1) * 16)) & 1u;
                am[((size_t)bs*1024 + qb + ql) * 1024 + kt*64 + nt*16 + l16]
                    = b ? 0.0f : acc[mt][nt][r] * 0.0625f;
            }
        }
}

// ---------------------------------------------------------------------------
extern "C" void kernel_launch(void* const* d_in, const int* in_sizes, int n_in,
                              void* d_out, int out_size, void* d_ws, size_t ws_size,
                              hipStream_t stream)
{
    const float* q    = (const float*)d_in[0];
    const float* k    = (const float*)d_in[1];
    const float* v    = (const float*)d_in[2];
    const float* mask = (const float*)d_in[3];
    const float* wq   = (const float*)d_in[4];
    const float* bq   = (const float*)d_in[5];
    const float* wk   = (const float*)d_in[6];
    const float* bk   = (const float*)d_in[7];
    const float* wv   = (const float*)d_in[8];
    const float* bv   = (const float*)d_in[9];
    const float* wo   = (const float*)d_in[10];
    const float* bo   = (const float*)d_in[11];

    const size_t TEN = (size_t)16384 * 1024;       // 16.78M elements
    char* w = (char*)d_ws;
    h16* qf  = (h16*)w;             w += TEN * 2;  // inputs, fp16
    h16* kf  = (h16*)w;             w += TEN * 2;
    h16* vf  = (h16*)w;             w += TEN * 2;
    h16* wqT = (h16*)w;             w += (size_t)1024*1024*2;
    h16* wkT = (h16*)w;             w += (size_t)1024*1024*2;
    h16* wvT = (h16*)w;             w += (size_t)1024*1024*2;
    h16* woT = (h16*)w;             w += (size_t)1024*1024*2;
    h16* qhh = (h16*)w;             w += TEN * 2;  // [bsh][l][64], pre-scaled
    h16* khh = (h16*)w;             w += TEN * 2;
    h16* vtt = (h16*)w;             w += TEN * 2;  // [bsh][64][l]
    h16* ctx = (h16*)w;             w += TEN * 2;  // [bs][l][1024]
    float* Lst = (float*)w;         w += (size_t)256 * 1024 * 4;   // [bsh][l], log2
    u64* mbits = (u64*)w;                          // [bs][l][16] qwords, 2MB

    float* out = (float*)d_out;
    float* am  = out + TEN;

    mkbits<<<65536, 256, 0, stream>>>(mask, mbits);
    cvt16<<<16384, 256, 0, stream>>>(q, qf);
    cvt16<<<16384, 256, 0, stream>>>(k, kf);
    cvt16<<<16384, 256, 0, stream>>>(v, vf);
    wtrans<<<dim3(16,16), 256, 0, stream>>>(wq, wqT);
    wtrans<<<dim3(16,16), 256, 0, stream>>>(wk, wkT);
    wtrans<<<dim3(16,16), 256, 0, stream>>>(wv, wvT);
    wtrans<<<dim3(16,16), 256, 0, stream>>>(wo, woT);
    proj<<<dim3(8,128), 256, 0, stream>>>(qf, wqT, bq, qhh, 0);
    proj<<<dim3(8,128), 256, 0, stream>>>(kf, wkT, bk, khh, 1);
    proj<<<dim3(8,128), 256, 0, stream>>>(vf, wvT, bv, vtt, 2);
    attn_ctx<<<dim3(256,8), 256, 0, stream>>>(qhh, khh, vtt, mbits, ctx, Lst);
    attn_mean_k<<<dim3(16,8,16), 256, 0, stream>>>(qhh, khh, mbits, Lst, am);
    proj<<<dim3(8,128), 256, 0, stream>>>(ctx, woT, bo, out, 3);
}

// Round 5
// 762.243 us; speedup vs baseline: 1.3498x; 1.0962x over previous
//
#include <hip/hip_runtime.h>

typedef _Float16 h16;
typedef _Float16 v8h __attribute__((ext_vector_type(8)));
typedef float    v4f __attribute__((ext_vector_type(4)));
typedef unsigned long long u64;

// qh is pre-scaled by SCALE*log2e = 0.125*1.4426950 at proj time, so
// softmax is p = exp2(s) with zero per-element scaling ops.
constexpr float QPRESCALE = 0.18033688f;

#define MFMA16(a,b,c) __builtin_amdgcn_mfma_f32_16x16x32_f16((a),(b),(c),0,0,0)

__device__ __forceinline__ float fexp2(float x) {
#if __has_builtin(__builtin_amdgcn_exp2f)
    return __builtin_amdgcn_exp2f(x);
#else
    return __expf(x * 0.69314718056f);
#endif
}
__device__ __forceinline__ float flog2(float x) {
#if __has_builtin(__builtin_amdgcn_logf)
    return __builtin_amdgcn_logf(x);
#else
    return __logf(x) * 1.44269504f;
#endif
}

// async global->LDS, 16B per lane. dst must be the WAVE-UNIFORM base; HW adds lane*16.
__device__ __forceinline__ void gld16(const h16* g, const h16* l)
{
    __builtin_amdgcn_global_load_lds(
        (const __attribute__((address_space(1))) void*)g,
        (__attribute__((address_space(3))) void*)l, 16, 0, 0);
}

// ---------------------------------------------------------------------------
// prep: fused fp32->fp16 cast of q/k/v (z=0..2) + mask bitmask build (z=3).
// z=3: each thread covers 4 elements -> 4 bits at offset (t&15)*4 of qword
// t>>4; OR-combined across 16 lanes via u64 shfl_xor butterfly.
// ---------------------------------------------------------------------------
__global__ __launch_bounds__(256)
void prep(const float* __restrict__ q, const float* __restrict__ k,
          const float* __restrict__ v, const float* __restrict__ mask,
          h16* __restrict__ qf, h16* __restrict__ kf, h16* __restrict__ vf,
          u64* __restrict__ mb)
{
    const int z = blockIdx.y;
    size_t t = (size_t)blockIdx.x * 256 + threadIdx.x;
    size_t i = t * 4;
    if (z < 3) {
        const float* x = (z == 0) ? q : (z == 1) ? k : v;
        h16* y        = (z == 0) ? qf : (z == 1) ? kf : vf;
        float4 vv = *(const float4*)(x + i);
        h16 o[4] = {(h16)vv.x, (h16)vv.y, (h16)vv.z, (h16)vv.w};
        *(uint2*)(y + i) = *(const uint2*)o;
    } else {
        float4 mv = *(const float4*)(mask + i);
        uint b4 = (mv.x != 0.0f ? 1u : 0u) | (mv.y != 0.0f ? 2u : 0u)
                | (mv.z != 0.0f ? 4u : 0u) | (mv.w != 0.0f ? 8u : 0u);
        u64 w = (u64)b4 << ((t & 15) * 4);
        w |= __shfl_xor(w, 1);
        w |= __shfl_xor(w, 2);
        w |= __shfl_xor(w, 4);
        w |= __shfl_xor(w, 8);
        if ((threadIdx.x & 15) == 0) mb[t >> 4] = w;
    }
}

// ---------------------------------------------------------------------------
// wtrans4: all 4 weight matrices fp32 -> fp16 transposed, z selects matrix.
// ---------------------------------------------------------------------------
__global__ __launch_bounds__(256)
void wtrans4(const float* __restrict__ w0, const float* __restrict__ w1,
             const float* __restrict__ w2, const float* __restrict__ w3,
             h16* __restrict__ t0, h16* __restrict__ t1,
             h16* __restrict__ t2, h16* __restrict__ t3)
{
    const int z = blockIdx.z;
    const float* W = (z == 0) ? w0 : (z == 1) ? w1 : (z == 2) ? w2 : w3;
    h16* WT        = (z == 0) ? t0 : (z == 1) ? t1 : (z == 2) ? t2 : t3;
    __shared__ float Ts[64][65];
    const int tid = threadIdx.x;
    const int n0 = blockIdx.x * 64, k0 = blockIdx.y * 64;
    #pragma unroll
    for (int i = 0; i < 4; ++i) {
        int f = tid + i * 256; int r = f >> 4, c = (f & 15) * 4;
        float4 v = *(const float4*)(W + (size_t)(k0 + r) * 1024 + n0 + c);
        Ts[r][c] = v.x; Ts[r][c+1] = v.y; Ts[r][c+2] = v.z; Ts[r][c+3] = v.w;
    }
    __syncthreads();
    #pragma unroll
    for (int i = 0; i < 4; ++i) {
        int f = tid + i * 256; int r = f >> 4, c = (f & 15) * 4;
        h16 o[4];
        #pragma unroll
        for (int j = 0; j < 4; ++j) o[j] = (h16)Ts[c + j][r];
        *(uint2*)(WT + (size_t)(n0 + r) * 1024 + k0 + c) = *(const uint2*)o;
    }
}

// ---------------------------------------------------------------------------
// Projection GEMM body: Y = A[16384,1024](fp16) @ BT^T + bias, 128x128 tile,
// 4 waves, m97-structure staging (global_load_lds width-16, linear LDS).
// XCD-aware block remap: lin%8 = XCD (HW round-robin); within an XCD, the 8
// n-blocks of one m-panel are CONSECUTIVE slots -> A panel fetched once.
// mode 0  : Y -> head-split fp16 [bs*16+h][l][64], PRE-SCALED by QPRESCALE (qh)
// mode 1  : Y -> head-split fp16 [bs*16+h][l][64]   (kh)
// mode 2  : Y -> transposed fp16 [bs*16+h][64][l]   (vt, for PV B-operand)
// mode 3  : Y -> fp32 row-major  [m][1024]          (final output)
// ---------------------------------------------------------------------------
__device__ __forceinline__
void proj_body(const h16* __restrict__ A, const h16* __restrict__ BT,
               const float* __restrict__ bias, void* __restrict__ out,
               int mode, int lin)
{
    __shared__ h16 As[128 * 32];
    __shared__ h16 Bs[128 * 32];
    const int tid  = threadIdx.x;
    const int lane = tid & 63, wv = tid >> 6;
    const int quad = lane >> 4, l16 = lane & 15;
    const int xcd = lin & 7, slot = lin >> 3;
    const int m0 = (xcd * 16 + (slot >> 3)) * 128;
    const int n0 = (slot & 7) * 128;
    const int wm = (wv & 1) * 64, wn = (wv >> 1) * 64;
    const int sr = wv * 16 + (lane >> 2);
    const int sc = (lane & 3) * 8;
    v4f acc[4][4] = {};
    for (int k0 = 0; k0 < 1024; k0 += 32) {
        #pragma unroll
        for (int i = 0; i < 2; ++i) {
            int r = i * 64 + sr;
            gld16(A  + (size_t)(m0 + r) * 1024 + k0 + sc, &As[i * 2048 + wv * 512]);
            gld16(BT + (size_t)(n0 + r) * 1024 + k0 + sc, &Bs[i * 2048 + wv * 512]);
        }
        __syncthreads();
        v8h af[4], bf[4];
        #pragma unroll
        for (int t = 0; t < 4; ++t) {
            af[t] = *(v8h*)&As[(wm + t*16 + l16) * 32 + quad * 8];
            bf[t] = *(v8h*)&Bs[(wn + t*16 + l16) * 32 + quad * 8];
        }
        #pragma unroll
        for (int mt = 0; mt < 4; ++mt)
            #pragma unroll
            for (int nt = 0; nt < 4; ++nt)
                acc[mt][nt] = MFMA16(af[mt], bf[nt], acc[mt][nt]);
        __syncthreads();
    }
    #pragma unroll
    for (int mt = 0; mt < 4; ++mt) {
        int mbase = m0 + wm + mt*16 + quad*4;
        #pragma unroll
        for (int nt = 0; nt < 4; ++nt) {
            int n = n0 + wn + nt*16 + l16;
            float bv = bias[n];
            #pragma unroll
            for (int r = 0; r < 4; ++r) {
                float y = acc[mt][nt][r] + bv;
                if (mode == 0) y *= QPRESCALE;
                int mm = mbase + r;
                int bs = mm >> 10, l = mm & 1023, h = n >> 6, d = n & 63;
                if (mode <= 1)
                    ((h16*)out)[(((size_t)bs*16 + h) * 1024 + l) * 64 + d] = (h16)y;
                else if (mode == 2)
                    ((h16*)out)[(((size_t)bs*16 + h) * 64 + d) * 1024 + l] = (h16)y;
                else
                    ((float*)out)[(size_t)mm * 1024 + n] = y;
            }
        }
    }
}

// fused q/k/v projections: blockIdx.y = which projection (0=q,1=k,2=v)
__global__ __launch_bounds__(256)
void proj3(const h16* __restrict__ qf, const h16* __restrict__ kf,
           const h16* __restrict__ vf,
           const h16* __restrict__ wqT, const h16* __restrict__ wkT,
           const h16* __restrict__ wvT,
           const float* __restrict__ bq, const float* __restrict__ bk,
           const float* __restrict__ bv,
           h16* __restrict__ qhh, h16* __restrict__ khh, h16* __restrict__ vtt)
{
    const int z = blockIdx.y;
    const h16* A   = (z == 0) ? qf  : (z == 1) ? kf  : vf;
    const h16* BT  = (z == 0) ? wqT : (z == 1) ? wkT : wvT;
    const float* b = (z == 0) ? bq  : (z == 1) ? bk  : bv;
    h16* o         = (z == 0) ? qhh : (z == 1) ? khh : vtt;
    proj_body(A, BT, b, o, z, blockIdx.x);
}

// output projection (fp32 out)
__global__ __launch_bounds__(256)
void projo(const h16* __restrict__ A, const h16* __restrict__ BT,
           const float* __restrict__ bias, float* __restrict__ out)
{
    proj_body(A, BT, bias, out, 3, blockIdx.x);
}

// ---------------------------------------------------------------------------
// Fused attention. qh pre-scaled -> p = exp2(S). Row sums via ones-column
// MFMA. K/V reg-prefetched one tile ahead. 3 barriers/kt (R2-proven form).
// XCD remap: the 8 q-blocks of one bsh are CONSECUTIVE slots on one XCD
// -> K/V stay L2-resident across their reuse. T5 setprio around MFMA.
// Lst stores log2(rowsum) for the attn_mean pass.
// NOTE: VGPR=84 sits exactly at the 24-waves/CU cliff - do not add registers.
// ---------------------------------------------------------------------------
__global__ __launch_bounds__(256, 3)
void attn_ctx(const h16* __restrict__ qh, const h16* __restrict__ kh,
              const h16* __restrict__ vt, const u64* __restrict__ mbits,
              h16* __restrict__ ctx, float* __restrict__ Lst)
{
    __shared__ h16 Qs[128][68];
    __shared__ h16 Ks[64][68];
    __shared__ h16 Vs[64][68];
    __shared__ h16 Ps[128][68];
    const int tid  = threadIdx.x;
    const int lane = tid & 63, wv = tid >> 6;
    const int quad = lane >> 4, l16 = lane & 15;
    // XCD remap: xcd = orig&7; within an XCD, qb varies fastest (8 consecutive
    // slots share one bsh => its 256KB K/V is L2-resident while reused).
    const int orig = blockIdx.x + (blockIdx.y << 8);
    const int slot = orig >> 3;
    const int bsh  = (orig & 7) + ((slot >> 3) << 3);
    const int qb   = (slot & 7) << 7;
    const int bs = bsh >> 4, h = bsh & 15;
    const int qw = wv * 32;
    const int fr = tid >> 3, fc = (tid & 7) * 8;

    // prefetch k-tile 0 into regs
    uint4 rK0 = *(const uint4*)(kh + ((size_t)bsh*1024 + fr     ) * 64 + fc);
    uint4 rK1 = *(const uint4*)(kh + ((size_t)bsh*1024 + fr + 32) * 64 + fc);
    uint4 rV0 = *(const uint4*)(vt + ((size_t)bsh*64 + fr     ) * 1024 + fc);
    uint4 rV1 = *(const uint4*)(vt + ((size_t)bsh*64 + fr + 32) * 1024 + fc);

    #pragma unroll
    for (int i = 0; i < 4; ++i) {
        int f = tid + i * 256; int r = f >> 3, c = (f & 7) * 8;
        *(uint4*)&Qs[r][c] = *(const uint4*)(qh + ((size_t)bsh*1024 + qb + r) * 64 + c);
    }
    v8h bones;
    {
        h16 o = (l16 == 0) ? (h16)1.0f : (h16)0.0f;
        #pragma unroll
        for (int j = 0; j < 8; ++j) bones[j] = o;
    }
    const u64* mrb = mbits + ((size_t)bs*1024 + qb + qw + quad*4) * 16;

    v4f accp[2][4] = {};
    v4f accs[2] = {};
    for (int kt = 0; kt < 16; ++kt) {
        __syncthreads();
        *(uint4*)&Ks[fr     ][fc] = rK0;
        *(uint4*)&Ks[fr + 32][fc] = rK1;
        *(uint4*)&Vs[fr     ][fc] = rV0;
        *(uint4*)&Vs[fr + 32][fc] = rV1;
        if (kt < 15) {   // issue next tile; latency hides under QK+softmax+PV
            rK0 = *(const uint4*)(kh + ((size_t)bsh*1024 + (kt+1)*64 + fr     ) * 64 + fc);
            rK1 = *(const uint4*)(kh + ((size_t)bsh*1024 + (kt+1)*64 + fr + 32) * 64 + fc);
            rV0 = *(const uint4*)(vt + ((size_t)bsh*64 + fr     ) * 1024 + (kt+1)*64 + fc);
            rV1 = *(const uint4*)(vt + ((size_t)bsh*64 + fr + 32) * 1024 + (kt+1)*64 + fc);
        }
        __syncthreads();
        v4f s[2][4] = {};
        __builtin_amdgcn_s_setprio(1);
        #pragma unroll
        for (int kc = 0; kc < 2; ++kc) {
            v8h aq[2], bk[4];
            aq[0] = *(v8h*)&Qs[qw      + l16][kc*32 + quad*8];
            aq[1] = *(v8h*)&Qs[qw + 16 + l16][kc*32 + quad*8];
            #pragma unroll
            for (int nt = 0; nt < 4; ++nt)
                bk[nt] = *(v8h*)&Ks[nt*16 + l16][kc*32 + quad*8];
            #pragma unroll
            for (int mt = 0; mt < 2; ++mt)
                #pragma unroll
                for (int nt = 0; nt < 4; ++nt)
                    s[mt][nt] = MFMA16(aq[mt], bk[nt], s[mt][nt]);
        }
        __builtin_amdgcn_s_setprio(0);
        #pragma unroll
        for (int mt = 0; mt < 2; ++mt)
            #pragma unroll
            for (int r = 0; r < 4; ++r) {
                int ql = qw + mt*16 + quad*4 + r;
                u64 m64 = mrb[(mt*16 + r) * 16 + kt];
                uint lo = (uint)(m64 >> l16);
                uint hi = (uint)(m64 >> (l16 + 32));
                #pragma unroll
                for (int nt = 0; nt < 4; ++nt) {
                    uint b = (((nt & 2) ? hi : lo) >> ((nt & 1) * 16)) & 1u;
                    float p = b ? 0.0f : fexp2(s[mt][nt][r]);
                    Ps[ql][nt*16 + l16] = (h16)p;
                }
            }
        __syncthreads();
        __builtin_amdgcn_s_setprio(1);
        #pragma unroll
        for (int kc = 0; kc < 2; ++kc) {
            v8h ap[2], bv[4];
            ap[0] = *(v8h*)&Ps[qw      + l16][kc*32 + quad*8];
            ap[1] = *(v8h*)&Ps[qw + 16 + l16][kc*32 + quad*8];
            #pragma unroll
            for (int nt = 0; nt < 4; ++nt)
                bv[nt] = *(v8h*)&Vs[nt*16 + l16][kc*32 + quad*8];
            #pragma unroll
            for (int mt = 0; mt < 2; ++mt) {
                accs[mt] = MFMA16(ap[mt], bones, accs[mt]);   // row sums
                #pragma unroll
                for (int nt = 0; nt < 4; ++nt)
                    accp[mt][nt] = MFMA16(ap[mt], bv[nt], accp[mt][nt]);
            }
        }
        __builtin_amdgcn_s_setprio(0);
    }
    // row sums live in l16==0 lanes of accs: store log2(l), broadcast, normalize.
    float lq[8];
    #pragma unroll
    for (int mt = 0; mt < 2; ++mt)
        #pragma unroll
        for (int r = 0; r < 4; ++r)
            lq[mt*4 + r] = accs[mt][r];
    if (l16 == 0) {
        #pragma unroll
        for (int j = 0; j < 8; ++j)
            Lst[(size_t)bsh*1024 + qb + qw + (j >> 2)*16 + quad*4 + (j & 3)]
                = flog2(lq[j]);
    }
    float rcp[8];
    #pragma unroll
    for (int j = 0; j < 8; ++j) {
        float l = __shfl(lq[j], quad * 16);
        rcp[j] = 1.0f / l;
    }
    #pragma unroll
    for (int mt = 0; mt < 2; ++mt)
        #pragma unroll
        for (int nt = 0; nt < 4; ++nt) {
            int dep = nt*16 + l16;
            #pragma unroll
            for (int r = 0; r < 4; ++r) {
                int ql = qw + mt*16 + quad*4 + r;
                float y = accp[mt][nt][r] * rcp[mt*4 + r];
                ctx[((size_t)bs*1024 + qb + ql) * 1024 + h*64 + dep] = (h16)y;
            }
        }
}

// ---------------------------------------------------------------------------
// attn_mean: per (bs, 128-q block, 64-k tile) loop all 16 heads in-block.
// Lst holds log2(l) -> inner loop is sub+exp2+add only. Synchronous LDS
// staging (NO cross-iteration reg prefetch: spilled acc in R3). mrow bitmask
// loaded AFTER the h-loop. XCD remap: one bs per XCD run, kt fastest.
// ---------------------------------------------------------------------------
__global__ __launch_bounds__(256)
void attn_mean_k(const h16* __restrict__ qh, const h16* __restrict__ kh,
                 const u64* __restrict__ mbits, const float* __restrict__ Lst,
                 float* __restrict__ am)
{
    __shared__ h16 Qs[128][68];
    __shared__ h16 Ks[64][68];
    const int tid  = threadIdx.x;
    const int lane = tid & 63, wv = tid >> 6;
    const int quad = lane >> 4, l16 = lane & 15;
    // XCD remap: xcd = orig&7; slot walks kt fastest, then qb, then bs-half.
    const int orig = blockIdx.x + (blockIdx.y << 4) + (blockIdx.z << 7);
    const int slot = orig >> 3;
    const int bs   = ((orig & 7) << 1) + (slot >> 7);
    const int kt   = slot & 15;
    const int qb   = ((slot >> 4) & 7) << 7;
    const int qw = wv * 32;
    float acc[2][4][4] = {};
    for (int h = 0; h < 16; ++h) {
        const int bsh = bs * 16 + h;
        __syncthreads();
        #pragma unroll
        for (int i = 0; i < 4; ++i) {
            int f = tid + i * 256; int r = f >> 3, c = (f & 7) * 8;
            *(uint4*)&Qs[r][c] = *(const uint4*)(qh + ((size_t)bsh*1024 + qb + r) * 64 + c);
        }
        #pragma unroll
        for (int i = 0; i < 2; ++i) {
            int f = tid + i * 256; int r = f >> 3, c = (f & 7) * 8;
            *(uint4*)&Ks[r][c] = *(const uint4*)(kh + ((size_t)bsh*1024 + kt*64 + r) * 64 + c);
        }
        __syncthreads();
        v4f s[2][4] = {};
        #pragma unroll
        for (int kc = 0; kc < 2; ++kc) {
            v8h aq[2], bk[4];
            aq[0] = *(v8h*)&Qs[qw      + l16][kc*32 + quad*8];
            aq[1] = *(v8h*)&Qs[qw + 16 + l16][kc*32 + quad*8];
            #pragma unroll
            for (int nt = 0; nt < 4; ++nt)
                bk[nt] = *(v8h*)&Ks[nt*16 + l16][kc*32 + quad*8];
            #pragma unroll
            for (int mt = 0; mt < 2; ++mt)
                #pragma unroll
                for (int nt = 0; nt < 4; ++nt)
                    s[mt][nt] = MFMA16(aq[mt], bk[nt], s[mt][nt]);
        }
        float ll[8];
        #pragma unroll
        for (int mt = 0; mt < 2; ++mt)
            #pragma unroll
            for (int r = 0; r < 4; ++r)
                ll[mt*4+r] = Lst[(size_t)bsh*1024 + qb + qw + mt*16 + quad*4 + r];
        #pragma unroll
        for (int mt = 0; mt < 2; ++mt)
            #pragma unroll
            for (int nt = 0; nt < 4; ++nt)
                #pragma unroll
                for (int r = 0; r < 4; ++r)
                    acc[mt][nt][r] += fexp2(s[mt][nt][r] - ll[mt*4+r]);
    }
    #pragma unroll
    for (int mt = 0; mt < 2; ++mt)
        #pragma unroll
        for (int r = 0; r < 4; ++r) {
            int ql = qw + mt*16 + quad*4 + r;
            u64 m64 = mbits[((size_t)bs*1024 + qb + ql) * 16 + kt];
            uint lo = (uint)(m64 >> l16);
            uint hi = (uint)(m64 >> (l16 + 32));
            #pragma unroll
            for (int nt = 0; nt < 4; ++nt) {
                uint b = (((nt & 2) ? hi : lo) >> ((nt & 1) * 16)) & 1u;
                am[((size_t)bs*1024 + qb + ql) * 1024 + kt*64 + nt*16 + l16]
                    = b ? 0.0f : acc[mt][nt][r] * 0.0625f;
            }
        }
}

// ---------------------------------------------------------------------------
extern "C" void kernel_launch(void* const* d_in, const int* in_sizes, int n_in,
                              void* d_out, int out_size, void* d_ws, size_t ws_size,
                              hipStream_t stream)
{
    const float* q    = (const float*)d_in[0];
    const float* k    = (const float*)d_in[1];
    const float* v    = (const float*)d_in[2];
    const float* mask = (const float*)d_in[3];
    const float* wq   = (const float*)d_in[4];
    const float* bq   = (const float*)d_in[5];
    const float* wk   = (const float*)d_in[6];
    const float* bk   = (const float*)d_in[7];
    const float* wv   = (const float*)d_in[8];
    const float* bv   = (const float*)d_in[9];
    const float* wo   = (const float*)d_in[10];
    const float* bo   = (const float*)d_in[11];

    const size_t TEN = (size_t)16384 * 1024;       // 16.78M elements
    char* w = (char*)d_ws;
    h16* qf  = (h16*)w;             w += TEN * 2;  // inputs, fp16
    h16* kf  = (h16*)w;             w += TEN * 2;
    h16* vf  = (h16*)w;             w += TEN * 2;
    h16* wqT = (h16*)w;             w += (size_t)1024*1024*2;
    h16* wkT = (h16*)w;             w += (size_t)1024*1024*2;
    h16* wvT = (h16*)w;             w += (size_t)1024*1024*2;
    h16* woT = (h16*)w;             w += (size_t)1024*1024*2;
    h16* qhh = (h16*)w;             w += TEN * 2;  // [bsh][l][64], pre-scaled
    h16* khh = (h16*)w;             w += TEN * 2;
    h16* vtt = (h16*)w;             w += TEN * 2;  // [bsh][64][l]
    h16* ctx = (h16*)w;             w += TEN * 2;  // [bs][l][1024]
    float* Lst = (float*)w;         w += (size_t)256 * 1024 * 4;   // [bsh][l], log2
    u64* mbits = (u64*)w;                          // [bs][l][16] qwords, 2MB

    float* out = (float*)d_out;
    float* am  = out + TEN;

    prep<<<dim3(16384, 4), 256, 0, stream>>>(q, k, v, mask, qf, kf, vf, mbits);
    wtrans4<<<dim3(16, 16, 4), 256, 0, stream>>>(wq, wk, wv, wo, wqT, wkT, wvT, woT);
    proj3<<<dim3(1024, 3), 256, 0, stream>>>(qf, kf, vf, wqT, wkT, wvT,
                                             bq, bk, bv, qhh, khh, vtt);
    attn_ctx<<<dim3(256, 8), 256, 0, stream>>>(qhh, khh, vtt, mbits, ctx, Lst);
    attn_mean_k<<<dim3(16, 8, 16), 256, 0, stream>>>(qhh, khh, mbits, Lst, am);
    projo<<<1024, 256, 0, stream>>>(ctx, woT, bo, out);
}